// Round 13
// baseline (983.976 us; speedup 1.0000x reference)
//
#include <hip/hip_runtime.h>
#include <cstdint>
#include <cstddef>

#define SL 2048
#define BS 2
#define NH 32
#define HD 128
#define HS 4096
#define NTOK 4096   // BS*SL
#define LDQ 12288   // fused QKV row stride (3*HS)

typedef __attribute__((ext_vector_type(8))) short short8;
typedef __attribute__((ext_vector_type(4))) float f32x4;
typedef __attribute__((ext_vector_type(4))) unsigned short u16x4;
typedef __attribute__((ext_vector_type(8))) unsigned short u16x8;

static __device__ __forceinline__ unsigned short f2bf(float f) {
    unsigned int u = __builtin_bit_cast(unsigned int, f);
    u = u + 0x7FFFu + ((u >> 16) & 1u);   // RNE
    return (unsigned short)(u >> 16);
}
static __device__ __forceinline__ float bf2f(unsigned short h) {
    unsigned int u = ((unsigned int)h) << 16;
    return __builtin_bit_cast(float, u);
}
static __device__ __forceinline__ float fexp2(float x) {
    return __builtin_amdgcn_exp2f(x);   // v_exp_f32 (base-2)
}

static __device__ __forceinline__ f32x4 mfma16(short8 a, short8 b, f32x4 c) {
    return __builtin_amdgcn_mfma_f32_16x16x32_bf16(a, b, c, 0, 0, 0);
}

static __device__ __forceinline__ void gload_lds16(const void* g, void* dst) {
    __builtin_amdgcn_global_load_lds(
        (const __attribute__((address_space(1))) unsigned int*)g,
        (__attribute__((address_space(3))) unsigned int*)dst,
        16, 0, 0);
}

// ---------------- fp32 -> bf16 convert (X) ----------------
__global__ void k_convert(const float* __restrict__ in, unsigned short* __restrict__ out, int n8) {
    int stride = gridDim.x * blockDim.x;
    for (int i = blockIdx.x * blockDim.x + threadIdx.x; i < n8; i += stride) {
        const f32x4* p = (const f32x4*)in + (size_t)i * 2;
        f32x4 a = p[0], b = p[1];
        u16x8 o;
        o[0] = f2bf(a[0]); o[1] = f2bf(a[1]); o[2] = f2bf(a[2]); o[3] = f2bf(a[3]);
        o[4] = f2bf(b[0]); o[5] = f2bf(b[1]); o[6] = f2bf(b[2]); o[7] = f2bf(b[3]);
        *((u16x8*)out + i) = o;
    }
}

// ---------------- fp32 W[k][n] -> bf16 Wt[n][k], 4 matrices in one launch ----------------
__global__ void k_transpose_w4(const float* __restrict__ w0, const float* __restrict__ w1,
                               const float* __restrict__ w2, const float* __restrict__ w3,
                               unsigned short* __restrict__ wtbase) {
    __shared__ float t[32][33];
    int z = blockIdx.z;
    const float* w = (z == 0) ? w0 : (z == 1) ? w1 : (z == 2) ? w2 : w3;
    unsigned short* wt = wtbase + (size_t)z * HS * HS;
    int r0 = blockIdx.y << 5, c0 = blockIdx.x << 5;
    int tr = threadIdx.x >> 3;
    int tc = (threadIdx.x & 7) << 2;
    f32x4 v = *(const f32x4*)(w + (size_t)(r0 + tr) * HS + c0 + tc);
    t[tr][tc + 0] = v[0]; t[tr][tc + 1] = v[1]; t[tr][tc + 2] = v[2]; t[tr][tc + 3] = v[3];
    __syncthreads();
    u16x4 o;
    o[0] = f2bf(t[tc + 0][tr]); o[1] = f2bf(t[tc + 1][tr]);
    o[2] = f2bf(t[tc + 2][tr]); o[3] = f2bf(t[tc + 3][tr]);
    *(u16x4*)(wt + (size_t)(c0 + tr) * HS + r0 + tc) = o;
}

// =====================================================================
// 256x256 8-phase bf16 GEMM, single barrier per phase (verified R11),
// chunked XCD mapping (verified R12), NEW: vectorized epilogue — repack
// each wave's 16x64 f32 sub-tile through a padded [16][68] per-wave LDS
// region (dead 128KB reused after a barrier), then 16-element contiguous
// stores per lane (2x u16x8 bf16 / 4x f32x4 fp32).
// =====================================================================
#define REG(b, w) ((b) * 65536 + (w) * 16384)   // w: 0=A0 1=A1 2=B0 3=B1

template <typename OutT>
__global__ __launch_bounds__(512, 2) void k_gemm256(
    const unsigned short* __restrict__ A,
    const unsigned short* __restrict__ Bt,
    OutT* __restrict__ C,
    int M, int N, int K)
{
    __shared__ char lds[131072];
    char* ldsb = lds;
    int tiles_m = M >> 8, tiles_n = N >> 8;
    int xcd = blockIdx.x & 7, idx = blockIdx.x >> 3;
    int rows_per = tiles_m >> 1, cols_per = tiles_n >> 2;
    int cr = xcd >> 2, cc = xcd & 3;
    int tm = cr * rows_per + idx / cols_per;
    int tn = cc * cols_per + idx % cols_per;
    int tid = threadIdx.x, lane = tid & 63, wave = tid >> 6;
    int l15 = lane & 15, kh = lane >> 4;
    int wm = wave >> 2, wn = wave & 3;
    int row0 = tm << 8, col0 = tn << 8;
    f32x4 acc[8][4] = {};

    int sr = tid >> 3;
    int scb = (tid & 7) << 4;
    int scol = (scb ^ ((sr & 7) << 4)) >> 1;
    const unsigned short* Abase0 = A + (size_t)(row0 + sr) * K + scol;
    const unsigned short* Bbase0 = Bt + (size_t)(col0 + sr) * K + scol;

    int rswz = (l15 & 7) << 4;
    int afb = wm * 16384 + l15 * 128 + ((kh * 16) ^ rswz);
    int bfb = 32768 + ((wn >> 1) * 16384) + (((wn & 1) * 64 + l15) * 128) + ((kh * 16) ^ rswz);

    short8 af[4][2], bfr[4][2];

#define STAGE(R, Gp) do { \
    gload_lds16((Gp),                ldsb + (R) + tid * 16); \
    gload_lds16((Gp) + (size_t)64 * K, ldsb + (R) + 8192 + tid * 16); } while (0)

#define READ_A(buf, g) { _Pragma("unroll") for (int mq = 0; mq < 4; ++mq) \
    _Pragma("unroll") for (int ks = 0; ks < 2; ++ks) \
        af[mq][ks] = *(const short8*)(ldsb + (buf) * 65536 + ((afb + (g) * 8192 + mq * 2048) ^ (ks * 64))); }

#define READ_B2(buf, p) { _Pragma("unroll") for (int n = 2*(p); n < 2*(p)+2; ++n) \
    _Pragma("unroll") for (int ks = 0; ks < 2; ++ks) \
        bfr[n][ks] = *(const short8*)(ldsb + (buf) * 65536 + ((bfb + n * 2048) ^ (ks * 64))); }

#define MFMA_Q(g, nh) { _Pragma("unroll") for (int mq = 0; mq < 4; ++mq) \
    _Pragma("unroll") for (int n2 = 0; n2 < 2; ++n2) { \
        acc[(g)*4+mq][(nh)*2+n2] = mfma16(af[mq][0], bfr[(nh)*2+n2][0], acc[(g)*4+mq][(nh)*2+n2]); \
        acc[(g)*4+mq][(nh)*2+n2] = mfma16(af[mq][1], bfr[(nh)*2+n2][1], acc[(g)*4+mq][(nh)*2+n2]); } }

#define LGKM0() do { asm volatile("s_waitcnt lgkmcnt(0)" ::: "memory"); \
                     __builtin_amdgcn_sched_barrier(0); } while (0)
#define BAR() __builtin_amdgcn_s_barrier()
#define PRIO1() __builtin_amdgcn_s_setprio(1)
#define PRIO0() __builtin_amdgcn_s_setprio(0)
#define VM6() asm volatile("s_waitcnt vmcnt(6)" ::: "memory")
#define VM0() asm volatile("s_waitcnt vmcnt(0)" ::: "memory")

    // prologue: buf0 full tile0 + buf1 {B0,B1} of tile1 (12 loads)
    STAGE(REG(0, 2), Bbase0);
    STAGE(REG(0, 3), Bbase0 + (size_t)128 * K);
    STAGE(REG(0, 0), Abase0);
    STAGE(REG(0, 1), Abase0 + (size_t)128 * K);
    STAGE(REG(1, 2), Bbase0 + 64);
    STAGE(REG(1, 3), Bbase0 + (size_t)128 * K + 64);

    int nkt = K >> 6;
    int niter = nkt >> 1;
    #pragma unroll 1
    for (int t = 0; t < niter; ++t) {
        int kt1 = 2 * t + 1, kt2 = 2 * t + 2, kt3 = 2 * t + 3;
        bool s2 = kt2 < nkt, s3 = kt3 < nkt;
        // ---- ph1 (boundary, buf0): stage A0(b1,kt1); vmcnt; BAR; 12 reads ----
        STAGE(REG(1, 0), Abase0 + (size_t)kt1 * 64);
        VM6();
        BAR();
        READ_B2(0, 0); READ_A(0, 0); LGKM0();
        PRIO1(); MFMA_Q(0, 0); PRIO0();
        // ---- ph2 (interior): 4 reads; stage A1(b1,kt1) ----
        READ_B2(0, 1);
        STAGE(REG(1, 1), Abase0 + (size_t)128 * K + (size_t)kt1 * 64);
        BAR(); LGKM0();
        PRIO1(); MFMA_Q(0, 1); PRIO0();
        // ---- ph3 (interior): 8 reads; stage B0(b0,kt2) ----
        READ_A(0, 1);
        if (s2) STAGE(REG(0, 2), Bbase0 + (size_t)kt2 * 64);
        BAR(); LGKM0();
        PRIO1(); MFMA_Q(1, 0); PRIO0();
        // ---- ph4 (interior): 0 reads; stage B1(b0,kt2) ----
        if (s2) STAGE(REG(0, 3), Bbase0 + (size_t)128 * K + (size_t)kt2 * 64);
        BAR();
        PRIO1(); MFMA_Q(1, 1); PRIO0();
        // ---- ph5 (boundary, buf1): stage A0(b0,kt2); vmcnt; BAR; 12 reads ----
        if (s2) { STAGE(REG(0, 0), Abase0 + (size_t)kt2 * 64); VM6(); }
        else    { VM0(); }
        BAR();
        READ_B2(1, 0); READ_A(1, 0); LGKM0();
        PRIO1(); MFMA_Q(0, 0); PRIO0();
        // ---- ph6 (interior): 4 reads; stage A1(b0,kt2) ----
        READ_B2(1, 1);
        if (s2) STAGE(REG(0, 1), Abase0 + (size_t)128 * K + (size_t)kt2 * 64);
        BAR(); LGKM0();
        PRIO1(); MFMA_Q(0, 1); PRIO0();
        // ---- ph7 (interior): 8 reads; stage B0(b1,kt3) ----
        READ_A(1, 1);
        if (s3) STAGE(REG(1, 2), Bbase0 + (size_t)kt3 * 64);
        BAR(); LGKM0();
        PRIO1(); MFMA_Q(1, 0); PRIO0();
        // ---- ph8 (interior): 0 reads; stage B1(b1,kt3) ----
        if (s3) STAGE(REG(1, 3), Bbase0 + (size_t)128 * K + (size_t)kt3 * 64);
        BAR();
        PRIO1(); MFMA_Q(1, 1); PRIO0();
    }

    // ---- vectorized epilogue: repack through dead LDS ----
    BAR();   // every wave has consumed (lgkm0'd) its ds_reads -> lds reusable
    {
        float* ep = (float*)(ldsb + wave * 4352);   // [16][68] f32, 2-way banks
        int r16 = lane & 15, cg = lane >> 4;
        #pragma unroll 1
        for (int m = 0; m < 8; ++m) {
            #pragma unroll
            for (int n = 0; n < 4; ++n)
                #pragma unroll
                for (int rr = 0; rr < 4; ++rr)
                    ep[(kh * 4 + rr) * 68 + n * 16 + l15] = acc[m][n][rr];
            const float* src = ep + r16 * 68 + cg * 16;
            int row = row0 + wm * 128 + m * 16 + r16;
            int col = col0 + wn * 64 + cg * 16;
            if constexpr (sizeof(OutT) == 2) {
                u16x8 o0, o1;
                #pragma unroll
                for (int i = 0; i < 8; ++i) { o0[i] = f2bf(src[i]); o1[i] = f2bf(src[8 + i]); }
                *(u16x8*)((unsigned short*)C + (size_t)row * N + col) = o0;
                *(u16x8*)((unsigned short*)C + (size_t)row * N + col + 8) = o1;
            } else {
                #pragma unroll
                for (int i = 0; i < 4; ++i)
                    *(f32x4*)((float*)C + (size_t)row * N + col + i * 4) = *(const f32x4*)(src + i * 4);
            }
        }
    }
#undef STAGE
#undef READ_A
#undef READ_B2
#undef MFMA_Q
#undef LGKM0
#undef BAR
#undef PRIO1
#undef PRIO0
#undef VM6
#undef VM0
}

// ---------------- fused RoPE (blocks 0..8191) + V transpose (8192..24575) ----------------
__global__ void k_rope_tv(unsigned short* __restrict__ QKV, unsigned short* __restrict__ Vt) {
    __shared__ unsigned short t[32][36];
    if (blockIdx.x < 8192) {
        const float SCALE = 0.12751779544166854f;  // (1/sqrt(128)) * log2(e)
        int i = blockIdx.x * blockDim.x + threadIdx.x;
        int q4 = i & 15;
        int head = (i >> 4) & (NH - 1);
        int tok = i >> 9;
        int s = tok & (SL - 1);
        int d0 = q4 << 2;
        size_t base = (size_t)tok * LDQ + head * HD;
        unsigned short* Q = QKV + base;
        unsigned short* K = QKV + base + HS;
        float cs[4], sn[4];
        #pragma unroll
        for (int j = 0; j < 4; j++) {
            float invf = expf(-(float)(d0 + j) * 0.14391156831212787f);  // ln(1e4)/64
            float ang = (float)s * invf;
            sn[j] = sinf(ang); cs[j] = cosf(ang);
        }
        {
            u16x4 lo = *(u16x4*)(Q + d0);
            u16x4 hi = *(u16x4*)(Q + d0 + 64);
            u16x4 nlo, nhi;
            #pragma unroll
            for (int j = 0; j < 4; j++) {
                float x0 = bf2f(lo[j]), x1 = bf2f(hi[j]);
                nlo[j] = f2bf((x0 * cs[j] - x1 * sn[j]) * SCALE);
                nhi[j] = f2bf((x1 * cs[j] + x0 * sn[j]) * SCALE);
            }
            *(u16x4*)(Q + d0) = nlo;
            *(u16x4*)(Q + d0 + 64) = nhi;
        }
        {
            u16x4 lo = *(u16x4*)(K + d0);
            u16x4 hi = *(u16x4*)(K + d0 + 64);
            u16x4 nlo, nhi;
            #pragma unroll
            for (int j = 0; j < 4; j++) {
                float x0 = bf2f(lo[j]), x1 = bf2f(hi[j]);
                nlo[j] = f2bf(x0 * cs[j] - x1 * sn[j]);
                nhi[j] = f2bf(x1 * cs[j] + x0 * sn[j]);
            }
            *(u16x4*)(K + d0) = nlo;
            *(u16x4*)(K + d0 + 64) = nhi;
        }
    } else {
        int idx = blockIdx.x - 8192;            // 16384 blocks: 64 x 4 x 64
        int bh = idx >> 8;
        int b = bh >> 5, h = bh & 31;
        int s0 = (idx & 63) << 5, d0 = ((idx >> 6) & 3) << 5;
        int tr = threadIdx.x >> 3, tc = (threadIdx.x & 7) << 2;
        u16x4 v = *(const u16x4*)(QKV + (size_t)(b * SL + s0 + tr) * LDQ + 2 * HS + h * HD + d0 + tc);
        t[tr][tc + 0] = v[0]; t[tr][tc + 1] = v[1]; t[tr][tc + 2] = v[2]; t[tr][tc + 3] = v[3];
        __syncthreads();
        u16x4 o;
        o[0] = t[tc + 0][tr]; o[1] = t[tc + 1][tr]; o[2] = t[tc + 2][tr]; o[3] = t[tc + 3][tr];
        *(u16x4*)(Vt + ((size_t)(b * NH + h) * HD + d0 + tr) * SL + s0 + tc) = o;
    }
}

// ---------------- causal flash attention v7 ----------------
// v6 + K double-buffered -> ONE barrier per kt-iteration. Stage(kt+1)
// issued right after the barrier (targets buf^1, whose last reads were
// pre-barrier at kt-1: WAR-safe; RAW via the barrier's vmcnt drain).
// LDS 74.7 KB -> still 2 blocks/CU (16 waves).
__global__ __launch_bounds__(512, 4) void k_attn(
    const unsigned short* __restrict__ QKV,
    const unsigned short* __restrict__ Vt,
    unsigned short* __restrict__ O)
{
    __shared__ unsigned short Ks[2][64 * 128];   // 32 KB
    __shared__ unsigned short Vs[2][128 * 64];   // 32 KB
    __shared__ unsigned short Ps[8][16][36];     // 9 KB
    int qt = (int)(gridDim.x - 1) - (int)blockIdx.x;  // big q-tiles first
    int bh = blockIdx.y;
    int b = bh >> 5, h = bh & 31;
    int tid = threadIdx.x, lane = tid & 63, wave = tid >> 6;   // wave 0..7
    int l15 = lane & 15, kh = lane >> 4;
    int qrow0 = (qt << 7) + (wave << 4);
    short8 qf[4];
    {
        const unsigned short* qp = QKV + ((size_t)(b * SL) + qrow0 + l15) * LDQ + h * HD + kh * 8;
        #pragma unroll
        for (int f = 0; f < 4; ++f) qf[f] = *(const short8*)(qp + f * 32);
    }
    f32x4 oacc[8] = {};
    float m[4] = {-1e30f, -1e30f, -1e30f, -1e30f};
    float lsum[4] = {0.f, 0.f, 0.f, 0.f};
    int ksrow = tid >> 4, kchunk = tid & 15;   // K: 2 chunks x 32 rows
    int vsrow = tid >> 3, vchunk = tid & 7;    // V: 2 chunks x 64 rows
    const unsigned short* Kbase = QKV + HS + (size_t)(b * SL) * LDQ + h * HD;
    const unsigned short* Vbase = Vt + (size_t)(b * NH + h) * HD * (size_t)SL;
    int ktmax = (qt << 1) + 1;

    // prologue: stage K(0), V(0) into buf 0
    #pragma unroll
    for (int c = 0; c < 2; ++c) {
        int kr = c * 32 + ksrow;
        gload_lds16(Kbase + (size_t)kr * LDQ + ((kchunk ^ (kr & 7)) << 3),
                    (char*)Ks[0] + c * 8192 + tid * 16);
        int vr = c * 64 + vsrow;
        gload_lds16(Vbase + (size_t)vr * SL + ((vchunk ^ (vr & 7)) << 3),
                    (char*)Vs[0] + c * 8192 + tid * 16);
    }
    int buf = 0;
    for (int kt = 0; kt <= ktmax; ++kt) {
        __syncthreads();   // stages for kt complete (vmcnt drain); buf^1 reads all pre-barrier
        if (kt < ktmax) {  // issue next stage immediately -> overlaps whole iteration
            #pragma unroll
            for (int c = 0; c < 2; ++c) {
                int kr = c * 32 + ksrow;
                gload_lds16(Kbase + (size_t)(((kt + 1) << 6) + kr) * LDQ + ((kchunk ^ (kr & 7)) << 3),
                            (char*)Ks[buf ^ 1] + c * 8192 + tid * 16);
                int vr = c * 64 + vsrow;
                gload_lds16(Vbase + (size_t)vr * SL + ((kt + 1) << 6) + ((vchunk ^ (vr & 7)) << 3),
                            (char*)Vs[buf ^ 1] + c * 8192 + tid * 16);
            }
        }
        bool active = (kt << 6) <= qrow0 + 15;
        if (active) {
            f32x4 sfr[4];
            __builtin_amdgcn_s_setprio(1);
            #pragma unroll
            for (int c = 0; c < 4; ++c) {
                f32x4 acc = {};
                int krow = c * 16 + l15;
                #pragma unroll
                for (int f = 0; f < 4; ++f) {
                    short8 kf = *(const short8*)((const char*)Ks[buf] + krow * 256 + ((((f << 2) + kh) ^ (krow & 7)) << 4));
                    acc = mfma16(qf[f], kf, acc);
                }
                sfr[c] = acc;
            }
            __builtin_amdgcn_s_setprio(0);
            float pm[4] = {-1e30f, -1e30f, -1e30f, -1e30f};
            bool domask = ((kt << 6) + 63) > qrow0;
            if (domask) {
                #pragma unroll
                for (int c = 0; c < 4; ++c) {
                    int kkg = (kt << 6) + c * 16 + l15;
                    #pragma unroll
                    for (int r = 0; r < 4; ++r) {
                        int qg = qrow0 + kh * 4 + r;
                        float v = sfr[c][r];
                        v = (kkg > qg) ? -1e30f : v;
                        sfr[c][r] = v;
                        pm[r] = fmaxf(pm[r], v);
                    }
                }
            } else {
                #pragma unroll
                for (int c = 0; c < 4; ++c)
                    #pragma unroll
                    for (int r = 0; r < 4; ++r) pm[r] = fmaxf(pm[r], sfr[c][r]);
            }
            #pragma unroll
            for (int off = 1; off < 16; off <<= 1)
                #pragma unroll
                for (int r = 0; r < 4; ++r) pm[r] = fmaxf(pm[r], __shfl_xor(pm[r], off, 64));
            bool ok = true;
            #pragma unroll
            for (int r = 0; r < 4; ++r) ok = ok && (pm[r] <= m[r] + 11.5f);
            if (!__all(ok)) {
                #pragma unroll
                for (int r = 0; r < 4; ++r) {
                    float mn = fmaxf(m[r], pm[r]);
                    float alpha = fexp2(m[r] - mn);
                    m[r] = mn;
                    lsum[r] *= alpha;
                    #pragma unroll
                    for (int db = 0; db < 8; ++db) oacc[db][r] *= alpha;
                }
            }
            float rs[4] = {0.f, 0.f, 0.f, 0.f};
            #pragma unroll
            for (int c = 0; c < 4; ++c)
                #pragma unroll
                for (int r = 0; r < 4; ++r) {
                    float p = fexp2(sfr[c][r] - m[r]);
                    sfr[c][r] = p;
                    rs[r] += p;
                }
            #pragma unroll
            for (int off = 1; off < 16; off <<= 1)
                #pragma unroll
                for (int r = 0; r < 4; ++r) rs[r] += __shfl_xor(rs[r], off, 64);
            #pragma unroll
            for (int r = 0; r < 4; ++r) lsum[r] += rs[r];
            short8 pa[2];
            #pragma unroll
            for (int half = 0; half < 2; ++half) {
                #pragma unroll
                for (int c = 0; c < 2; ++c)
                    #pragma unroll
                    for (int r = 0; r < 4; ++r)
                        Ps[wave][kh * 4 + r][c * 16 + l15] = f2bf(sfr[half * 2 + c][r]);
                pa[half] = *(const short8*)(&Ps[wave][l15][kh * 8]);
            }
            const char* vb = (const char*)Vs[buf];
            __builtin_amdgcn_s_setprio(1);
            #pragma unroll
            for (int db = 0; db < 8; ++db) {
                int vrow = db * 16 + l15;
                #pragma unroll
                for (int f = 0; f < 2; ++f) {
                    short8 vf = *(const short8*)(vb + vrow * 128 + ((((f << 2) + kh) ^ (vrow & 7)) << 4));
                    oacc[db] = mfma16(pa[f], vf, oacc[db]);
                }
            }
            __builtin_amdgcn_s_setprio(0);
        }
        buf ^= 1;
    }
    #pragma unroll
    for (int db = 0; db < 8; ++db)
        #pragma unroll
        for (int r = 0; r < 4; ++r) {
            int qg = qrow0 + kh * 4 + r;
            float v = oacc[db][r] / lsum[r];
            O[((size_t)(b * SL) + qg) * HS + h * HD + db * 16 + l15] = f2bf(v);
        }
}

extern "C" void kernel_launch(void* const* d_in, const int* in_sizes, int n_in,
                              void* d_out, int out_size, void* d_ws, size_t ws_size,
                              hipStream_t stream)
{
    const float* X  = (const float*)d_in[0];
    const float* Wq = (const float*)d_in[1];
    const float* Wk = (const float*)d_in[2];
    const float* Wv = (const float*)d_in[3];
    const float* Wo = (const float*)d_in[4];
    float* out = (float*)d_out;
    const size_t SLAB = (size_t)NTOK * HS * 2;  // 32 MiB per bf16 slab
    char* ws = (char*)d_ws;
    unsigned short* Xb  = (unsigned short*)(ws + 0 * SLAB);
    unsigned short* Wqt = (unsigned short*)(ws + 1 * SLAB);  // Wqt|Wkt|Wvt contiguous = fused B^T
    unsigned short* Wot = (unsigned short*)(ws + 4 * SLAB);
    unsigned short* QKV = (unsigned short*)(ws + 5 * SLAB);  // 96 MiB: [4096][12288]
    unsigned short* Vtb = Xb;   // alias: Xb dead after fused QKV GEMM
    unsigned short* Ob  = Wqt;  // alias: W*t dead after fused QKV GEMM

    k_convert<<<2048, 256, 0, stream>>>(X, Xb, NTOK * HS / 8);
    k_transpose_w4<<<dim3(128, 128, 4), 256, 0, stream>>>(Wq, Wk, Wv, Wo, Wqt);
    // fused QKV projection: C[4096][12288] = Xb * [Wqt|Wkt|Wvt]^T  (16x48=768 tiles)
    k_gemm256<unsigned short><<<768, 512, 0, stream>>>(Xb, Wqt, QKV, NTOK, 3 * HS, HS);
    // fused RoPE + V transpose (8192 + 16384 blocks)
    k_rope_tv<<<24576, 256, 0, stream>>>(QKV, Vtb);
    k_attn<<<dim3(SL / 128, BS * NH), 512, 0, stream>>>(QKV, Vtb, Ob);
    // output projection: out[4096][4096] = Ob * Wot^T  (16x16=256 tiles)
    k_gemm256<float><<<256, 512, 0, stream>>>(Ob, Wot, out, NTOK, HS, HS);
}

// Round 14
// 810.390 us; speedup vs baseline: 1.2142x; 1.2142x over previous
//
#include <hip/hip_runtime.h>
#include <cstdint>
#include <cstddef>

#define SL 2048
#define BS 2
#define NH 32
#define HD 128
#define HS 4096
#define NTOK 4096   // BS*SL
#define LDQ 12288   // fused QKV row stride (3*HS)

typedef __attribute__((ext_vector_type(8))) short short8;
typedef __attribute__((ext_vector_type(4))) float f32x4;
typedef __attribute__((ext_vector_type(4))) unsigned short u16x4;
typedef __attribute__((ext_vector_type(8))) unsigned short u16x8;

static __device__ __forceinline__ unsigned short f2bf(float f) {
    unsigned int u = __builtin_bit_cast(unsigned int, f);
    u = u + 0x7FFFu + ((u >> 16) & 1u);   // RNE
    return (unsigned short)(u >> 16);
}
static __device__ __forceinline__ float bf2f(unsigned short h) {
    unsigned int u = ((unsigned int)h) << 16;
    return __builtin_bit_cast(float, u);
}
static __device__ __forceinline__ float fexp2(float x) {
    return __builtin_amdgcn_exp2f(x);   // v_exp_f32 (base-2)
}

static __device__ __forceinline__ f32x4 mfma16(short8 a, short8 b, f32x4 c) {
    return __builtin_amdgcn_mfma_f32_16x16x32_bf16(a, b, c, 0, 0, 0);
}

static __device__ __forceinline__ void gload_lds16(const void* g, void* dst) {
    __builtin_amdgcn_global_load_lds(
        (const __attribute__((address_space(1))) unsigned int*)g,
        (__attribute__((address_space(3))) unsigned int*)dst,
        16, 0, 0);
}

// ---------------- fp32 -> bf16 convert (X) ----------------
__global__ void k_convert(const float* __restrict__ in, unsigned short* __restrict__ out, int n8) {
    int stride = gridDim.x * blockDim.x;
    for (int i = blockIdx.x * blockDim.x + threadIdx.x; i < n8; i += stride) {
        const f32x4* p = (const f32x4*)in + (size_t)i * 2;
        f32x4 a = p[0], b = p[1];
        u16x8 o;
        o[0] = f2bf(a[0]); o[1] = f2bf(a[1]); o[2] = f2bf(a[2]); o[3] = f2bf(a[3]);
        o[4] = f2bf(b[0]); o[5] = f2bf(b[1]); o[6] = f2bf(b[2]); o[7] = f2bf(b[3]);
        *((u16x8*)out + i) = o;
    }
}

// ---------------- fp32 W[k][n] -> bf16 Wt[n][k], 4 matrices in one launch ----------------
__global__ void k_transpose_w4(const float* __restrict__ w0, const float* __restrict__ w1,
                               const float* __restrict__ w2, const float* __restrict__ w3,
                               unsigned short* __restrict__ wtbase) {
    __shared__ float t[32][33];
    int z = blockIdx.z;
    const float* w = (z == 0) ? w0 : (z == 1) ? w1 : (z == 2) ? w2 : w3;
    unsigned short* wt = wtbase + (size_t)z * HS * HS;
    int r0 = blockIdx.y << 5, c0 = blockIdx.x << 5;
    int tr = threadIdx.x >> 3;
    int tc = (threadIdx.x & 7) << 2;
    f32x4 v = *(const f32x4*)(w + (size_t)(r0 + tr) * HS + c0 + tc);
    t[tr][tc + 0] = v[0]; t[tr][tc + 1] = v[1]; t[tr][tc + 2] = v[2]; t[tr][tc + 3] = v[3];
    __syncthreads();
    u16x4 o;
    o[0] = f2bf(t[tc + 0][tr]); o[1] = f2bf(t[tc + 1][tr]);
    o[2] = f2bf(t[tc + 2][tr]); o[3] = f2bf(t[tc + 3][tr]);
    *(u16x4*)(wt + (size_t)(c0 + tr) * HS + r0 + tc) = o;
}

// =====================================================================
// 256x256 8-phase bf16 GEMM, single barrier per phase (verified R11),
// chunked XCD mapping (verified R12), R12-exact scalar epilogue
// (R13's LDS-repack epilogue scattered 16B stores across 64 rows ->
// 5x write amplification; REVERTED).
// =====================================================================
#define REG(b, w) ((b) * 65536 + (w) * 16384)   // w: 0=A0 1=A1 2=B0 3=B1

template <typename OutT>
__global__ __launch_bounds__(512, 2) void k_gemm256(
    const unsigned short* __restrict__ A,
    const unsigned short* __restrict__ Bt,
    OutT* __restrict__ C,
    int M, int N, int K)
{
    __shared__ char lds[131072];
    char* ldsb = lds;
    int tiles_m = M >> 8, tiles_n = N >> 8;
    int xcd = blockIdx.x & 7, idx = blockIdx.x >> 3;
    int rows_per = tiles_m >> 1, cols_per = tiles_n >> 2;
    int cr = xcd >> 2, cc = xcd & 3;
    int tm = cr * rows_per + idx / cols_per;
    int tn = cc * cols_per + idx % cols_per;
    int tid = threadIdx.x, lane = tid & 63, wave = tid >> 6;
    int l15 = lane & 15, kh = lane >> 4;
    int wm = wave >> 2, wn = wave & 3;
    int row0 = tm << 8, col0 = tn << 8;
    f32x4 acc[8][4] = {};

    int sr = tid >> 3;
    int scb = (tid & 7) << 4;
    int scol = (scb ^ ((sr & 7) << 4)) >> 1;
    const unsigned short* Abase0 = A + (size_t)(row0 + sr) * K + scol;
    const unsigned short* Bbase0 = Bt + (size_t)(col0 + sr) * K + scol;

    int rswz = (l15 & 7) << 4;
    int afb = wm * 16384 + l15 * 128 + ((kh * 16) ^ rswz);
    int bfb = 32768 + ((wn >> 1) * 16384) + (((wn & 1) * 64 + l15) * 128) + ((kh * 16) ^ rswz);

    short8 af[4][2], bfr[4][2];

#define STAGE(R, Gp) do { \
    gload_lds16((Gp),                ldsb + (R) + tid * 16); \
    gload_lds16((Gp) + (size_t)64 * K, ldsb + (R) + 8192 + tid * 16); } while (0)

#define READ_A(buf, g) { _Pragma("unroll") for (int mq = 0; mq < 4; ++mq) \
    _Pragma("unroll") for (int ks = 0; ks < 2; ++ks) \
        af[mq][ks] = *(const short8*)(ldsb + (buf) * 65536 + ((afb + (g) * 8192 + mq * 2048) ^ (ks * 64))); }

#define READ_B2(buf, p) { _Pragma("unroll") for (int n = 2*(p); n < 2*(p)+2; ++n) \
    _Pragma("unroll") for (int ks = 0; ks < 2; ++ks) \
        bfr[n][ks] = *(const short8*)(ldsb + (buf) * 65536 + ((bfb + n * 2048) ^ (ks * 64))); }

#define MFMA_Q(g, nh) { _Pragma("unroll") for (int mq = 0; mq < 4; ++mq) \
    _Pragma("unroll") for (int n2 = 0; n2 < 2; ++n2) { \
        acc[(g)*4+mq][(nh)*2+n2] = mfma16(af[mq][0], bfr[(nh)*2+n2][0], acc[(g)*4+mq][(nh)*2+n2]); \
        acc[(g)*4+mq][(nh)*2+n2] = mfma16(af[mq][1], bfr[(nh)*2+n2][1], acc[(g)*4+mq][(nh)*2+n2]); } }

#define LGKM0() do { asm volatile("s_waitcnt lgkmcnt(0)" ::: "memory"); \
                     __builtin_amdgcn_sched_barrier(0); } while (0)
#define BAR() __builtin_amdgcn_s_barrier()
#define PRIO1() __builtin_amdgcn_s_setprio(1)
#define PRIO0() __builtin_amdgcn_s_setprio(0)
#define VM6() asm volatile("s_waitcnt vmcnt(6)" ::: "memory")
#define VM0() asm volatile("s_waitcnt vmcnt(0)" ::: "memory")

    // prologue: buf0 full tile0 + buf1 {B0,B1} of tile1 (12 loads)
    STAGE(REG(0, 2), Bbase0);
    STAGE(REG(0, 3), Bbase0 + (size_t)128 * K);
    STAGE(REG(0, 0), Abase0);
    STAGE(REG(0, 1), Abase0 + (size_t)128 * K);
    STAGE(REG(1, 2), Bbase0 + 64);
    STAGE(REG(1, 3), Bbase0 + (size_t)128 * K + 64);

    int nkt = K >> 6;
    int niter = nkt >> 1;
    #pragma unroll 1
    for (int t = 0; t < niter; ++t) {
        int kt1 = 2 * t + 1, kt2 = 2 * t + 2, kt3 = 2 * t + 3;
        bool s2 = kt2 < nkt, s3 = kt3 < nkt;
        // ---- ph1 (boundary, buf0): stage A0(b1,kt1); vmcnt; BAR; 12 reads ----
        STAGE(REG(1, 0), Abase0 + (size_t)kt1 * 64);
        VM6();
        BAR();
        READ_B2(0, 0); READ_A(0, 0); LGKM0();
        PRIO1(); MFMA_Q(0, 0); PRIO0();
        // ---- ph2 (interior): 4 reads; stage A1(b1,kt1) ----
        READ_B2(0, 1);
        STAGE(REG(1, 1), Abase0 + (size_t)128 * K + (size_t)kt1 * 64);
        BAR(); LGKM0();
        PRIO1(); MFMA_Q(0, 1); PRIO0();
        // ---- ph3 (interior): 8 reads; stage B0(b0,kt2) ----
        READ_A(0, 1);
        if (s2) STAGE(REG(0, 2), Bbase0 + (size_t)kt2 * 64);
        BAR(); LGKM0();
        PRIO1(); MFMA_Q(1, 0); PRIO0();
        // ---- ph4 (interior): 0 reads; stage B1(b0,kt2) ----
        if (s2) STAGE(REG(0, 3), Bbase0 + (size_t)128 * K + (size_t)kt2 * 64);
        BAR();
        PRIO1(); MFMA_Q(1, 1); PRIO0();
        // ---- ph5 (boundary, buf1): stage A0(b0,kt2); vmcnt; BAR; 12 reads ----
        if (s2) { STAGE(REG(0, 0), Abase0 + (size_t)kt2 * 64); VM6(); }
        else    { VM0(); }
        BAR();
        READ_B2(1, 0); READ_A(1, 0); LGKM0();
        PRIO1(); MFMA_Q(0, 0); PRIO0();
        // ---- ph6 (interior): 4 reads; stage A1(b0,kt2) ----
        READ_B2(1, 1);
        if (s2) STAGE(REG(0, 1), Abase0 + (size_t)128 * K + (size_t)kt2 * 64);
        BAR(); LGKM0();
        PRIO1(); MFMA_Q(0, 1); PRIO0();
        // ---- ph7 (interior): 8 reads; stage B0(b1,kt3) ----
        READ_A(1, 1);
        if (s3) STAGE(REG(1, 2), Bbase0 + (size_t)kt3 * 64);
        BAR(); LGKM0();
        PRIO1(); MFMA_Q(1, 0); PRIO0();
        // ---- ph8 (interior): 0 reads; stage B1(b1,kt3) ----
        if (s3) STAGE(REG(1, 3), Bbase0 + (size_t)128 * K + (size_t)kt3 * 64);
        BAR();
        PRIO1(); MFMA_Q(1, 1); PRIO0();
    }

    #pragma unroll
    for (int m = 0; m < 8; ++m)
        #pragma unroll
        for (int n = 0; n < 4; ++n)
            #pragma unroll
            for (int rr = 0; rr < 4; ++rr) {
                int row = row0 + wm * 128 + m * 16 + kh * 4 + rr;
                int col = col0 + wn * 64 + n * 16 + l15;
                float v = acc[m][n][rr];
                if constexpr (sizeof(OutT) == 2) C[(size_t)row * N + col] = (OutT)f2bf(v);
                else                             C[(size_t)row * N + col] = v;
            }
#undef STAGE
#undef READ_A
#undef READ_B2
#undef MFMA_Q
#undef LGKM0
#undef BAR
#undef PRIO1
#undef PRIO0
#undef VM6
#undef VM0
}

// ---------------- fused RoPE (blocks 0..8191) + V transpose (8192..24575) ----------------
__global__ void k_rope_tv(unsigned short* __restrict__ QKV, unsigned short* __restrict__ Vt) {
    __shared__ unsigned short t[32][36];
    if (blockIdx.x < 8192) {
        const float SCALE = 0.12751779544166854f;  // (1/sqrt(128)) * log2(e)
        int i = blockIdx.x * blockDim.x + threadIdx.x;
        int q4 = i & 15;
        int head = (i >> 4) & (NH - 1);
        int tok = i >> 9;
        int s = tok & (SL - 1);
        int d0 = q4 << 2;
        size_t base = (size_t)tok * LDQ + head * HD;
        unsigned short* Q = QKV + base;
        unsigned short* K = QKV + base + HS;
        float cs[4], sn[4];
        #pragma unroll
        for (int j = 0; j < 4; j++) {
            float invf = expf(-(float)(d0 + j) * 0.14391156831212787f);  // ln(1e4)/64
            float ang = (float)s * invf;
            sn[j] = sinf(ang); cs[j] = cosf(ang);
        }
        {
            u16x4 lo = *(u16x4*)(Q + d0);
            u16x4 hi = *(u16x4*)(Q + d0 + 64);
            u16x4 nlo, nhi;
            #pragma unroll
            for (int j = 0; j < 4; j++) {
                float x0 = bf2f(lo[j]), x1 = bf2f(hi[j]);
                nlo[j] = f2bf((x0 * cs[j] - x1 * sn[j]) * SCALE);
                nhi[j] = f2bf((x1 * cs[j] + x0 * sn[j]) * SCALE);
            }
            *(u16x4*)(Q + d0) = nlo;
            *(u16x4*)(Q + d0 + 64) = nhi;
        }
        {
            u16x4 lo = *(u16x4*)(K + d0);
            u16x4 hi = *(u16x4*)(K + d0 + 64);
            u16x4 nlo, nhi;
            #pragma unroll
            for (int j = 0; j < 4; j++) {
                float x0 = bf2f(lo[j]), x1 = bf2f(hi[j]);
                nlo[j] = f2bf(x0 * cs[j] - x1 * sn[j]);
                nhi[j] = f2bf(x1 * cs[j] + x0 * sn[j]);
            }
            *(u16x4*)(K + d0) = nlo;
            *(u16x4*)(K + d0 + 64) = nhi;
        }
    } else {
        int idx = blockIdx.x - 8192;            // 16384 blocks: 64 x 4 x 64
        int bh = idx >> 8;
        int b = bh >> 5, h = bh & 31;
        int s0 = (idx & 63) << 5, d0 = ((idx >> 6) & 3) << 5;
        int tr = threadIdx.x >> 3, tc = (threadIdx.x & 7) << 2;
        u16x4 v = *(const u16x4*)(QKV + (size_t)(b * SL + s0 + tr) * LDQ + 2 * HS + h * HD + d0 + tc);
        t[tr][tc + 0] = v[0]; t[tr][tc + 1] = v[1]; t[tr][tc + 2] = v[2]; t[tr][tc + 3] = v[3];
        __syncthreads();
        u16x4 o;
        o[0] = t[tc + 0][tr]; o[1] = t[tc + 1][tr]; o[2] = t[tc + 2][tr]; o[3] = t[tc + 3][tr];
        *(u16x4*)(Vt + ((size_t)(b * NH + h) * HD + d0 + tr) * SL + s0 + tc) = o;
    }
}

// ---------------- causal flash attention v7 (kept from R13) ----------------
// K+V double-buffered -> ONE barrier per kt-iteration. Stage(kt+1) issued
// right after the barrier (targets buf^1, whose last reads were pre-barrier
// at kt-1: WAR-safe; RAW via the barrier's vmcnt drain). 2 blocks/CU.
__global__ __launch_bounds__(512, 4) void k_attn(
    const unsigned short* __restrict__ QKV,
    const unsigned short* __restrict__ Vt,
    unsigned short* __restrict__ O)
{
    __shared__ unsigned short Ks[2][64 * 128];   // 32 KB
    __shared__ unsigned short Vs[2][128 * 64];   // 32 KB
    __shared__ unsigned short Ps[8][16][36];     // 9 KB
    int qt = (int)(gridDim.x - 1) - (int)blockIdx.x;  // big q-tiles first
    int bh = blockIdx.y;
    int b = bh >> 5, h = bh & 31;
    int tid = threadIdx.x, lane = tid & 63, wave = tid >> 6;   // wave 0..7
    int l15 = lane & 15, kh = lane >> 4;
    int qrow0 = (qt << 7) + (wave << 4);
    short8 qf[4];
    {
        const unsigned short* qp = QKV + ((size_t)(b * SL) + qrow0 + l15) * LDQ + h * HD + kh * 8;
        #pragma unroll
        for (int f = 0; f < 4; ++f) qf[f] = *(const short8*)(qp + f * 32);
    }
    f32x4 oacc[8] = {};
    float m[4] = {-1e30f, -1e30f, -1e30f, -1e30f};
    float lsum[4] = {0.f, 0.f, 0.f, 0.f};
    int ksrow = tid >> 4, kchunk = tid & 15;   // K: 2 chunks x 32 rows
    int vsrow = tid >> 3, vchunk = tid & 7;    // V: 2 chunks x 64 rows
    const unsigned short* Kbase = QKV + HS + (size_t)(b * SL) * LDQ + h * HD;
    const unsigned short* Vbase = Vt + (size_t)(b * NH + h) * HD * (size_t)SL;
    int ktmax = (qt << 1) + 1;

    // prologue: stage K(0), V(0) into buf 0
    #pragma unroll
    for (int c = 0; c < 2; ++c) {
        int kr = c * 32 + ksrow;
        gload_lds16(Kbase + (size_t)kr * LDQ + ((kchunk ^ (kr & 7)) << 3),
                    (char*)Ks[0] + c * 8192 + tid * 16);
        int vr = c * 64 + vsrow;
        gload_lds16(Vbase + (size_t)vr * SL + ((vchunk ^ (vr & 7)) << 3),
                    (char*)Vs[0] + c * 8192 + tid * 16);
    }
    int buf = 0;
    for (int kt = 0; kt <= ktmax; ++kt) {
        __syncthreads();   // stages for kt complete (vmcnt drain); buf^1 reads all pre-barrier
        if (kt < ktmax) {  // issue next stage immediately -> overlaps whole iteration
            #pragma unroll
            for (int c = 0; c < 2; ++c) {
                int kr = c * 32 + ksrow;
                gload_lds16(Kbase + (size_t)(((kt + 1) << 6) + kr) * LDQ + ((kchunk ^ (kr & 7)) << 3),
                            (char*)Ks[buf ^ 1] + c * 8192 + tid * 16);
                int vr = c * 64 + vsrow;
                gload_lds16(Vbase + (size_t)vr * SL + ((kt + 1) << 6) + ((vchunk ^ (vr & 7)) << 3),
                            (char*)Vs[buf ^ 1] + c * 8192 + tid * 16);
            }
        }
        bool active = (kt << 6) <= qrow0 + 15;
        if (active) {
            f32x4 sfr[4];
            __builtin_amdgcn_s_setprio(1);
            #pragma unroll
            for (int c = 0; c < 4; ++c) {
                f32x4 acc = {};
                int krow = c * 16 + l15;
                #pragma unroll
                for (int f = 0; f < 4; ++f) {
                    short8 kf = *(const short8*)((const char*)Ks[buf] + krow * 256 + ((((f << 2) + kh) ^ (krow & 7)) << 4));
                    acc = mfma16(qf[f], kf, acc);
                }
                sfr[c] = acc;
            }
            __builtin_amdgcn_s_setprio(0);
            float pm[4] = {-1e30f, -1e30f, -1e30f, -1e30f};
            bool domask = ((kt << 6) + 63) > qrow0;
            if (domask) {
                #pragma unroll
                for (int c = 0; c < 4; ++c) {
                    int kkg = (kt << 6) + c * 16 + l15;
                    #pragma unroll
                    for (int r = 0; r < 4; ++r) {
                        int qg = qrow0 + kh * 4 + r;
                        float v = sfr[c][r];
                        v = (kkg > qg) ? -1e30f : v;
                        sfr[c][r] = v;
                        pm[r] = fmaxf(pm[r], v);
                    }
                }
            } else {
                #pragma unroll
                for (int c = 0; c < 4; ++c)
                    #pragma unroll
                    for (int r = 0; r < 4; ++r) pm[r] = fmaxf(pm[r], sfr[c][r]);
            }
            #pragma unroll
            for (int off = 1; off < 16; off <<= 1)
                #pragma unroll
                for (int r = 0; r < 4; ++r) pm[r] = fmaxf(pm[r], __shfl_xor(pm[r], off, 64));
            bool ok = true;
            #pragma unroll
            for (int r = 0; r < 4; ++r) ok = ok && (pm[r] <= m[r] + 11.5f);
            if (!__all(ok)) {
                #pragma unroll
                for (int r = 0; r < 4; ++r) {
                    float mn = fmaxf(m[r], pm[r]);
                    float alpha = fexp2(m[r] - mn);
                    m[r] = mn;
                    lsum[r] *= alpha;
                    #pragma unroll
                    for (int db = 0; db < 8; ++db) oacc[db][r] *= alpha;
                }
            }
            float rs[4] = {0.f, 0.f, 0.f, 0.f};
            #pragma unroll
            for (int c = 0; c < 4; ++c)
                #pragma unroll
                for (int r = 0; r < 4; ++r) {
                    float p = fexp2(sfr[c][r] - m[r]);
                    sfr[c][r] = p;
                    rs[r] += p;
                }
            #pragma unroll
            for (int off = 1; off < 16; off <<= 1)
                #pragma unroll
                for (int r = 0; r < 4; ++r) rs[r] += __shfl_xor(rs[r], off, 64);
            #pragma unroll
            for (int r = 0; r < 4; ++r) lsum[r] += rs[r];
            short8 pa[2];
            #pragma unroll
            for (int half = 0; half < 2; ++half) {
                #pragma unroll
                for (int c = 0; c < 2; ++c)
                    #pragma unroll
                    for (int r = 0; r < 4; ++r)
                        Ps[wave][kh * 4 + r][c * 16 + l15] = f2bf(sfr[half * 2 + c][r]);
                pa[half] = *(const short8*)(&Ps[wave][l15][kh * 8]);
            }
            const char* vb = (const char*)Vs[buf];
            __builtin_amdgcn_s_setprio(1);
            #pragma unroll
            for (int db = 0; db < 8; ++db) {
                int vrow = db * 16 + l15;
                #pragma unroll
                for (int f = 0; f < 2; ++f) {
                    short8 vf = *(const short8*)(vb + vrow * 128 + ((((f << 2) + kh) ^ (vrow & 7)) << 4));
                    oacc[db] = mfma16(pa[f], vf, oacc[db]);
                }
            }
            __builtin_amdgcn_s_setprio(0);
        }
        buf ^= 1;
    }
    #pragma unroll
    for (int db = 0; db < 8; ++db)
        #pragma unroll
        for (int r = 0; r < 4; ++r) {
            int qg = qrow0 + kh * 4 + r;
            float v = oacc[db][r] / lsum[r];
            O[((size_t)(b * SL) + qg) * HS + h * HD + db * 16 + l15] = f2bf(v);
        }
}

extern "C" void kernel_launch(void* const* d_in, const int* in_sizes, int n_in,
                              void* d_out, int out_size, void* d_ws, size_t ws_size,
                              hipStream_t stream)
{
    const float* X  = (const float*)d_in[0];
    const float* Wq = (const float*)d_in[1];
    const float* Wk = (const float*)d_in[2];
    const float* Wv = (const float*)d_in[3];
    const float* Wo = (const float*)d_in[4];
    float* out = (float*)d_out;
    const size_t SLAB = (size_t)NTOK * HS * 2;  // 32 MiB per bf16 slab
    char* ws = (char*)d_ws;
    unsigned short* Xb  = (unsigned short*)(ws + 0 * SLAB);
    unsigned short* Wqt = (unsigned short*)(ws + 1 * SLAB);  // Wqt|Wkt|Wvt contiguous = fused B^T
    unsigned short* Wot = (unsigned short*)(ws + 4 * SLAB);
    unsigned short* QKV = (unsigned short*)(ws + 5 * SLAB);  // 96 MiB: [4096][12288]
    unsigned short* Vtb = Xb;   // alias: Xb dead after fused QKV GEMM
    unsigned short* Ob  = Wqt;  // alias: W*t dead after fused QKV GEMM

    k_convert<<<2048, 256, 0, stream>>>(X, Xb, NTOK * HS / 8);
    k_transpose_w4<<<dim3(128, 128, 4), 256, 0, stream>>>(Wq, Wk, Wv, Wo, Wqt);
    // fused QKV projection: C[4096][12288] = Xb * [Wqt|Wkt|Wvt]^T  (16x48=768 tiles)
    k_gemm256<unsigned short><<<768, 512, 0, stream>>>(Xb, Wqt, QKV, NTOK, 3 * HS, HS);
    // fused RoPE + V transpose (8192 + 16384 blocks)
    k_rope_tv<<<24576, 256, 0, stream>>>(QKV, Vtb);
    k_attn<<<dim3(SL / 128, BS * NH), 512, 0, stream>>>(QKV, Vtb, Ob);
    // output projection: out[4096][4096] = Ob * Wot^T  (16x16=256 tiles)
    k_gemm256<float><<<256, 512, 0, stream>>>(Ob, Wot, out, NTOK, HS, HS);
}

// Round 15
// 721.538 us; speedup vs baseline: 1.3637x; 1.1231x over previous
//
#include <hip/hip_runtime.h>
#include <cstdint>
#include <cstddef>

#define SL 2048
#define BS 2
#define NH 32
#define HD 128
#define HS 4096
#define NTOK 4096   // BS*SL
#define LDQ 12288   // fused QKV row stride (3*HS)

typedef __attribute__((ext_vector_type(8))) short short8;
typedef __attribute__((ext_vector_type(4))) float f32x4;
typedef __attribute__((ext_vector_type(4))) unsigned short u16x4;
typedef __attribute__((ext_vector_type(8))) unsigned short u16x8;

static __device__ __forceinline__ unsigned short f2bf(float f) {
    unsigned int u = __builtin_bit_cast(unsigned int, f);
    u = u + 0x7FFFu + ((u >> 16) & 1u);   // RNE
    return (unsigned short)(u >> 16);
}
static __device__ __forceinline__ float bf2f(unsigned short h) {
    unsigned int u = ((unsigned int)h) << 16;
    return __builtin_bit_cast(float, u);
}
static __device__ __forceinline__ float fexp2(float x) {
    return __builtin_amdgcn_exp2f(x);   // v_exp_f32 (base-2)
}

static __device__ __forceinline__ f32x4 mfma16(short8 a, short8 b, f32x4 c) {
    return __builtin_amdgcn_mfma_f32_16x16x32_bf16(a, b, c, 0, 0, 0);
}

static __device__ __forceinline__ void gload_lds16(const void* g, void* dst) {
    __builtin_amdgcn_global_load_lds(
        (const __attribute__((address_space(1))) unsigned int*)g,
        (__attribute__((address_space(3))) unsigned int*)dst,
        16, 0, 0);
}

// ---------------- fused prep: W transposes (blocks 0..65535) + X convert (65536..67583) ----------------
__global__ void k_prep(const float* __restrict__ X, unsigned short* __restrict__ Xb,
                       const float* __restrict__ w0, const float* __restrict__ w1,
                       const float* __restrict__ w2, const float* __restrict__ w3,
                       unsigned short* __restrict__ wtbase) {
    __shared__ float t[32][33];
    if (blockIdx.x < 65536) {
        int z = blockIdx.x >> 14;
        const float* w = (z == 0) ? w0 : (z == 1) ? w1 : (z == 2) ? w2 : w3;
        unsigned short* wt = wtbase + (size_t)z * HS * HS;
        int r0 = ((blockIdx.x >> 7) & 127) << 5, c0 = (blockIdx.x & 127) << 5;
        int tr = threadIdx.x >> 3;
        int tc = (threadIdx.x & 7) << 2;
        f32x4 v = *(const f32x4*)(w + (size_t)(r0 + tr) * HS + c0 + tc);
        t[tr][tc + 0] = v[0]; t[tr][tc + 1] = v[1]; t[tr][tc + 2] = v[2]; t[tr][tc + 3] = v[3];
        __syncthreads();
        u16x4 o;
        o[0] = f2bf(t[tc + 0][tr]); o[1] = f2bf(t[tc + 1][tr]);
        o[2] = f2bf(t[tc + 2][tr]); o[3] = f2bf(t[tc + 3][tr]);
        *(u16x4*)(wt + (size_t)(c0 + tr) * HS + r0 + tc) = o;
    } else {
        int n8 = NTOK * HS / 8;
        int stride = 2048 * 256;
        for (int i = (blockIdx.x - 65536) * 256 + threadIdx.x; i < n8; i += stride) {
            const f32x4* p = (const f32x4*)X + (size_t)i * 2;
            f32x4 a = p[0], b = p[1];
            u16x8 o;
            o[0] = f2bf(a[0]); o[1] = f2bf(a[1]); o[2] = f2bf(a[2]); o[3] = f2bf(a[3]);
            o[4] = f2bf(b[0]); o[5] = f2bf(b[1]); o[6] = f2bf(b[2]); o[7] = f2bf(b[3]);
            *((u16x8*)Xb + i) = o;
        }
    }
}

// =====================================================================
// 256x256 8-phase bf16 GEMM (verified R11/R12/R14 state, byte-identical)
// =====================================================================
#define REG(b, w) ((b) * 65536 + (w) * 16384)   // w: 0=A0 1=A1 2=B0 3=B1

template <typename OutT>
__global__ __launch_bounds__(512, 2) void k_gemm256(
    const unsigned short* __restrict__ A,
    const unsigned short* __restrict__ Bt,
    OutT* __restrict__ C,
    int M, int N, int K)
{
    __shared__ char lds[131072];
    char* ldsb = lds;
    int tiles_m = M >> 8, tiles_n = N >> 8;
    int xcd = blockIdx.x & 7, idx = blockIdx.x >> 3;
    int rows_per = tiles_m >> 1, cols_per = tiles_n >> 2;
    int cr = xcd >> 2, cc = xcd & 3;
    int tm = cr * rows_per + idx / cols_per;
    int tn = cc * cols_per + idx % cols_per;
    int tid = threadIdx.x, lane = tid & 63, wave = tid >> 6;
    int l15 = lane & 15, kh = lane >> 4;
    int wm = wave >> 2, wn = wave & 3;
    int row0 = tm << 8, col0 = tn << 8;
    f32x4 acc[8][4] = {};

    int sr = tid >> 3;
    int scb = (tid & 7) << 4;
    int scol = (scb ^ ((sr & 7) << 4)) >> 1;
    const unsigned short* Abase0 = A + (size_t)(row0 + sr) * K + scol;
    const unsigned short* Bbase0 = Bt + (size_t)(col0 + sr) * K + scol;

    int rswz = (l15 & 7) << 4;
    int afb = wm * 16384 + l15 * 128 + ((kh * 16) ^ rswz);
    int bfb = 32768 + ((wn >> 1) * 16384) + (((wn & 1) * 64 + l15) * 128) + ((kh * 16) ^ rswz);

    short8 af[4][2], bfr[4][2];

#define STAGE(R, Gp) do { \
    gload_lds16((Gp),                ldsb + (R) + tid * 16); \
    gload_lds16((Gp) + (size_t)64 * K, ldsb + (R) + 8192 + tid * 16); } while (0)

#define READ_A(buf, g) { _Pragma("unroll") for (int mq = 0; mq < 4; ++mq) \
    _Pragma("unroll") for (int ks = 0; ks < 2; ++ks) \
        af[mq][ks] = *(const short8*)(ldsb + (buf) * 65536 + ((afb + (g) * 8192 + mq * 2048) ^ (ks * 64))); }

#define READ_B2(buf, p) { _Pragma("unroll") for (int n = 2*(p); n < 2*(p)+2; ++n) \
    _Pragma("unroll") for (int ks = 0; ks < 2; ++ks) \
        bfr[n][ks] = *(const short8*)(ldsb + (buf) * 65536 + ((bfb + n * 2048) ^ (ks * 64))); }

#define MFMA_Q(g, nh) { _Pragma("unroll") for (int mq = 0; mq < 4; ++mq) \
    _Pragma("unroll") for (int n2 = 0; n2 < 2; ++n2) { \
        acc[(g)*4+mq][(nh)*2+n2] = mfma16(af[mq][0], bfr[(nh)*2+n2][0], acc[(g)*4+mq][(nh)*2+n2]); \
        acc[(g)*4+mq][(nh)*2+n2] = mfma16(af[mq][1], bfr[(nh)*2+n2][1], acc[(g)*4+mq][(nh)*2+n2]); } }

#define LGKM0() do { asm volatile("s_waitcnt lgkmcnt(0)" ::: "memory"); \
                     __builtin_amdgcn_sched_barrier(0); } while (0)
#define BAR() __builtin_amdgcn_s_barrier()
#define PRIO1() __builtin_amdgcn_s_setprio(1)
#define PRIO0() __builtin_amdgcn_s_setprio(0)
#define VM6() asm volatile("s_waitcnt vmcnt(6)" ::: "memory")
#define VM0() asm volatile("s_waitcnt vmcnt(0)" ::: "memory")

    // prologue: buf0 full tile0 + buf1 {B0,B1} of tile1 (12 loads)
    STAGE(REG(0, 2), Bbase0);
    STAGE(REG(0, 3), Bbase0 + (size_t)128 * K);
    STAGE(REG(0, 0), Abase0);
    STAGE(REG(0, 1), Abase0 + (size_t)128 * K);
    STAGE(REG(1, 2), Bbase0 + 64);
    STAGE(REG(1, 3), Bbase0 + (size_t)128 * K + 64);

    int nkt = K >> 6;
    int niter = nkt >> 1;
    #pragma unroll 1
    for (int t = 0; t < niter; ++t) {
        int kt1 = 2 * t + 1, kt2 = 2 * t + 2, kt3 = 2 * t + 3;
        bool s2 = kt2 < nkt, s3 = kt3 < nkt;
        // ---- ph1 (boundary, buf0): stage A0(b1,kt1); vmcnt; BAR; 12 reads ----
        STAGE(REG(1, 0), Abase0 + (size_t)kt1 * 64);
        VM6();
        BAR();
        READ_B2(0, 0); READ_A(0, 0); LGKM0();
        PRIO1(); MFMA_Q(0, 0); PRIO0();
        // ---- ph2 (interior): 4 reads; stage A1(b1,kt1) ----
        READ_B2(0, 1);
        STAGE(REG(1, 1), Abase0 + (size_t)128 * K + (size_t)kt1 * 64);
        BAR(); LGKM0();
        PRIO1(); MFMA_Q(0, 1); PRIO0();
        // ---- ph3 (interior): 8 reads; stage B0(b0,kt2) ----
        READ_A(0, 1);
        if (s2) STAGE(REG(0, 2), Bbase0 + (size_t)kt2 * 64);
        BAR(); LGKM0();
        PRIO1(); MFMA_Q(1, 0); PRIO0();
        // ---- ph4 (interior): 0 reads; stage B1(b0,kt2) ----
        if (s2) STAGE(REG(0, 3), Bbase0 + (size_t)128 * K + (size_t)kt2 * 64);
        BAR();
        PRIO1(); MFMA_Q(1, 1); PRIO0();
        // ---- ph5 (boundary, buf1): stage A0(b0,kt2); vmcnt; BAR; 12 reads ----
        if (s2) { STAGE(REG(0, 0), Abase0 + (size_t)kt2 * 64); VM6(); }
        else    { VM0(); }
        BAR();
        READ_B2(1, 0); READ_A(1, 0); LGKM0();
        PRIO1(); MFMA_Q(0, 0); PRIO0();
        // ---- ph6 (interior): 4 reads; stage A1(b0,kt2) ----
        READ_B2(1, 1);
        if (s2) STAGE(REG(0, 1), Abase0 + (size_t)128 * K + (size_t)kt2 * 64);
        BAR(); LGKM0();
        PRIO1(); MFMA_Q(0, 1); PRIO0();
        // ---- ph7 (interior): 8 reads; stage B0(b1,kt3) ----
        READ_A(1, 1);
        if (s3) STAGE(REG(1, 2), Bbase0 + (size_t)kt3 * 64);
        BAR(); LGKM0();
        PRIO1(); MFMA_Q(1, 0); PRIO0();
        // ---- ph8 (interior): 0 reads; stage B1(b1,kt3) ----
        if (s3) STAGE(REG(1, 3), Bbase0 + (size_t)128 * K + (size_t)kt3 * 64);
        BAR();
        PRIO1(); MFMA_Q(1, 1); PRIO0();
    }

    #pragma unroll
    for (int m = 0; m < 8; ++m)
        #pragma unroll
        for (int n = 0; n < 4; ++n)
            #pragma unroll
            for (int rr = 0; rr < 4; ++rr) {
                int row = row0 + wm * 128 + m * 16 + kh * 4 + rr;
                int col = col0 + wn * 64 + n * 16 + l15;
                float v = acc[m][n][rr];
                if constexpr (sizeof(OutT) == 2) C[(size_t)row * N + col] = (OutT)f2bf(v);
                else                             C[(size_t)row * N + col] = v;
            }
#undef STAGE
#undef READ_A
#undef READ_B2
#undef MFMA_Q
#undef LGKM0
#undef BAR
#undef PRIO1
#undef PRIO0
#undef VM6
#undef VM0
}

// ---------------- fused RoPE (blocks 0..8191) + V transpose (8192..24575) ----------------
__global__ void k_rope_tv(unsigned short* __restrict__ QKV, unsigned short* __restrict__ Vt) {
    __shared__ unsigned short t[32][36];
    if (blockIdx.x < 8192) {
        const float SCALE = 0.12751779544166854f;  // (1/sqrt(128)) * log2(e)
        int i = blockIdx.x * blockDim.x + threadIdx.x;
        int q4 = i & 15;
        int head = (i >> 4) & (NH - 1);
        int tok = i >> 9;
        int s = tok & (SL - 1);
        int d0 = q4 << 2;
        size_t base = (size_t)tok * LDQ + head * HD;
        unsigned short* Q = QKV + base;
        unsigned short* K = QKV + base + HS;
        float cs[4], sn[4];
        #pragma unroll
        for (int j = 0; j < 4; j++) {
            float invf = expf(-(float)(d0 + j) * 0.14391156831212787f);  // ln(1e4)/64
            float ang = (float)s * invf;
            sn[j] = sinf(ang); cs[j] = cosf(ang);
        }
        {
            u16x4 lo = *(u16x4*)(Q + d0);
            u16x4 hi = *(u16x4*)(Q + d0 + 64);
            u16x4 nlo, nhi;
            #pragma unroll
            for (int j = 0; j < 4; j++) {
                float x0 = bf2f(lo[j]), x1 = bf2f(hi[j]);
                nlo[j] = f2bf((x0 * cs[j] - x1 * sn[j]) * SCALE);
                nhi[j] = f2bf((x1 * cs[j] + x0 * sn[j]) * SCALE);
            }
            *(u16x4*)(Q + d0) = nlo;
            *(u16x4*)(Q + d0 + 64) = nhi;
        }
        {
            u16x4 lo = *(u16x4*)(K + d0);
            u16x4 hi = *(u16x4*)(K + d0 + 64);
            u16x4 nlo, nhi;
            #pragma unroll
            for (int j = 0; j < 4; j++) {
                float x0 = bf2f(lo[j]), x1 = bf2f(hi[j]);
                nlo[j] = f2bf(x0 * cs[j] - x1 * sn[j]);
                nhi[j] = f2bf(x1 * cs[j] + x0 * sn[j]);
            }
            *(u16x4*)(K + d0) = nlo;
            *(u16x4*)(K + d0 + 64) = nhi;
        }
    } else {
        int idx = blockIdx.x - 8192;            // 16384 blocks: 64 x 4 x 64
        int bh = idx >> 8;
        int b = bh >> 5, h = bh & 31;
        int s0 = (idx & 63) << 5, d0 = ((idx >> 6) & 3) << 5;
        int tr = threadIdx.x >> 3, tc = (threadIdx.x & 7) << 2;
        u16x4 v = *(const u16x4*)(QKV + (size_t)(b * SL + s0 + tr) * LDQ + 2 * HS + h * HD + d0 + tc);
        t[tr][tc + 0] = v[0]; t[tr][tc + 1] = v[1]; t[tr][tc + 2] = v[2]; t[tr][tc + 3] = v[3];
        __syncthreads();
        u16x4 o;
        o[0] = t[tc + 0][tr]; o[1] = t[tc + 1][tr]; o[2] = t[tc + 2][tr]; o[3] = t[tc + 3][tr];
        *(u16x4*)(Vt + ((size_t)(b * NH + h) * HD + d0 + tr) * SL + s0 + tc) = o;
    }
}

// ---------------- causal flash attention v8 ----------------
// v7 + lazy cross-lane softmax:
//  - defer-max check on PER-LANE maxima (__all is equivalent to checking the
//    reduced max); the 4-round shfl max-reduce moves inside the rare rescale
//    branch.
//  - lsum kept as per-lane partial sums (alpha is row-uniform -> commutes);
//    reduced once in the epilogue before the divide.
// Common-path iteration loses ~8 shfl-rounds x 4 regs.
__global__ __launch_bounds__(512, 4) void k_attn(
    const unsigned short* __restrict__ QKV,
    const unsigned short* __restrict__ Vt,
    unsigned short* __restrict__ O)
{
    __shared__ unsigned short Ks[2][64 * 128];   // 32 KB
    __shared__ unsigned short Vs[2][128 * 64];   // 32 KB
    __shared__ unsigned short Ps[8][16][36];     // 9 KB
    int qt = (int)(gridDim.x - 1) - (int)blockIdx.x;  // big q-tiles first
    int bh = blockIdx.y;
    int b = bh >> 5, h = bh & 31;
    int tid = threadIdx.x, lane = tid & 63, wave = tid >> 6;   // wave 0..7
    int l15 = lane & 15, kh = lane >> 4;
    int qrow0 = (qt << 7) + (wave << 4);
    short8 qf[4];
    {
        const unsigned short* qp = QKV + ((size_t)(b * SL) + qrow0 + l15) * LDQ + h * HD + kh * 8;
        #pragma unroll
        for (int f = 0; f < 4; ++f) qf[f] = *(const short8*)(qp + f * 32);
    }
    f32x4 oacc[8] = {};
    float m[4] = {-1e30f, -1e30f, -1e30f, -1e30f};
    float lsum[4] = {0.f, 0.f, 0.f, 0.f};       // per-lane partial sums
    int ksrow = tid >> 4, kchunk = tid & 15;   // K: 2 chunks x 32 rows
    int vsrow = tid >> 3, vchunk = tid & 7;    // V: 2 chunks x 64 rows
    const unsigned short* Kbase = QKV + HS + (size_t)(b * SL) * LDQ + h * HD;
    const unsigned short* Vbase = Vt + (size_t)(b * NH + h) * HD * (size_t)SL;
    int ktmax = (qt << 1) + 1;

    // prologue: stage K(0), V(0) into buf 0
    #pragma unroll
    for (int c = 0; c < 2; ++c) {
        int kr = c * 32 + ksrow;
        gload_lds16(Kbase + (size_t)kr * LDQ + ((kchunk ^ (kr & 7)) << 3),
                    (char*)Ks[0] + c * 8192 + tid * 16);
        int vr = c * 64 + vsrow;
        gload_lds16(Vbase + (size_t)vr * SL + ((vchunk ^ (vr & 7)) << 3),
                    (char*)Vs[0] + c * 8192 + tid * 16);
    }
    int buf = 0;
    for (int kt = 0; kt <= ktmax; ++kt) {
        __syncthreads();   // stages for kt complete (vmcnt drain); buf^1 reads all pre-barrier
        if (kt < ktmax) {  // issue next stage immediately -> overlaps whole iteration
            #pragma unroll
            for (int c = 0; c < 2; ++c) {
                int kr = c * 32 + ksrow;
                gload_lds16(Kbase + (size_t)(((kt + 1) << 6) + kr) * LDQ + ((kchunk ^ (kr & 7)) << 3),
                            (char*)Ks[buf ^ 1] + c * 8192 + tid * 16);
                int vr = c * 64 + vsrow;
                gload_lds16(Vbase + (size_t)vr * SL + ((kt + 1) << 6) + ((vchunk ^ (vr & 7)) << 3),
                            (char*)Vs[buf ^ 1] + c * 8192 + tid * 16);
            }
        }
        bool active = (kt << 6) <= qrow0 + 15;
        if (active) {
            f32x4 sfr[4];
            __builtin_amdgcn_s_setprio(1);
            #pragma unroll
            for (int c = 0; c < 4; ++c) {
                f32x4 acc = {};
                int krow = c * 16 + l15;
                #pragma unroll
                for (int f = 0; f < 4; ++f) {
                    short8 kf = *(const short8*)((const char*)Ks[buf] + krow * 256 + ((((f << 2) + kh) ^ (krow & 7)) << 4));
                    acc = mfma16(qf[f], kf, acc);
                }
                sfr[c] = acc;
            }
            __builtin_amdgcn_s_setprio(0);
            // per-lane max over this tile's 4 columns (no shfl in common path)
            float pm[4] = {-1e30f, -1e30f, -1e30f, -1e30f};
            bool domask = ((kt << 6) + 63) > qrow0;
            if (domask) {
                #pragma unroll
                for (int c = 0; c < 4; ++c) {
                    int kkg = (kt << 6) + c * 16 + l15;
                    #pragma unroll
                    for (int r = 0; r < 4; ++r) {
                        int qg = qrow0 + kh * 4 + r;
                        float v = sfr[c][r];
                        v = (kkg > qg) ? -1e30f : v;
                        sfr[c][r] = v;
                        pm[r] = fmaxf(pm[r], v);
                    }
                }
            } else {
                #pragma unroll
                for (int c = 0; c < 4; ++c)
                    #pragma unroll
                    for (int r = 0; r < 4; ++r) pm[r] = fmaxf(pm[r], sfr[c][r]);
            }
            // lazy defer-max: per-lane check; reduce only on (rare) failure
            bool ok = true;
            #pragma unroll
            for (int r = 0; r < 4; ++r) ok = ok && (pm[r] <= m[r] + 11.5f);
            if (!__all(ok)) {
                #pragma unroll
                for (int off = 1; off < 16; off <<= 1)
                    #pragma unroll
                    for (int r = 0; r < 4; ++r) pm[r] = fmaxf(pm[r], __shfl_xor(pm[r], off, 64));
                #pragma unroll
                for (int r = 0; r < 4; ++r) {
                    float mn = fmaxf(m[r], pm[r]);
                    float alpha = fexp2(m[r] - mn);
                    m[r] = mn;
                    lsum[r] *= alpha;
                    #pragma unroll
                    for (int db = 0; db < 8; ++db) oacc[db][r] *= alpha;
                }
            }
            // P = exp2(S - m); accumulate per-lane partial lsum
            #pragma unroll
            for (int c = 0; c < 4; ++c)
                #pragma unroll
                for (int r = 0; r < 4; ++r) {
                    float p = fexp2(sfr[c][r] - m[r]);
                    sfr[c][r] = p;
                    lsum[r] += p;
                }
            short8 pa[2];
            #pragma unroll
            for (int half = 0; half < 2; ++half) {
                #pragma unroll
                for (int c = 0; c < 2; ++c)
                    #pragma unroll
                    for (int r = 0; r < 4; ++r)
                        Ps[wave][kh * 4 + r][c * 16 + l15] = f2bf(sfr[half * 2 + c][r]);
                pa[half] = *(const short8*)(&Ps[wave][l15][kh * 8]);
            }
            const char* vb = (const char*)Vs[buf];
            __builtin_amdgcn_s_setprio(1);
            #pragma unroll
            for (int db = 0; db < 8; ++db) {
                int vrow = db * 16 + l15;
                #pragma unroll
                for (int f = 0; f < 2; ++f) {
                    short8 vf = *(const short8*)(vb + vrow * 128 + ((((f << 2) + kh) ^ (vrow & 7)) << 4));
                    oacc[db] = mfma16(pa[f], vf, oacc[db]);
                }
            }
            __builtin_amdgcn_s_setprio(0);
        }
        buf ^= 1;
    }
    // epilogue: reduce the per-lane partial sums once, then divide
    #pragma unroll
    for (int off = 1; off < 16; off <<= 1)
        #pragma unroll
        for (int r = 0; r < 4; ++r) lsum[r] += __shfl_xor(lsum[r], off, 64);
    #pragma unroll
    for (int db = 0; db < 8; ++db)
        #pragma unroll
        for (int r = 0; r < 4; ++r) {
            int qg = qrow0 + kh * 4 + r;
            float v = oacc[db][r] / lsum[r];
            O[((size_t)(b * SL) + qg) * HS + h * HD + db * 16 + l15] = f2bf(v);
        }
}

extern "C" void kernel_launch(void* const* d_in, const int* in_sizes, int n_in,
                              void* d_out, int out_size, void* d_ws, size_t ws_size,
                              hipStream_t stream)
{
    const float* X  = (const float*)d_in[0];
    const float* Wq = (const float*)d_in[1];
    const float* Wk = (const float*)d_in[2];
    const float* Wv = (const float*)d_in[3];
    const float* Wo = (const float*)d_in[4];
    float* out = (float*)d_out;
    const size_t SLAB = (size_t)NTOK * HS * 2;  // 32 MiB per bf16 slab
    char* ws = (char*)d_ws;
    unsigned short* Xb  = (unsigned short*)(ws + 0 * SLAB);
    unsigned short* Wqt = (unsigned short*)(ws + 1 * SLAB);  // Wqt|Wkt|Wvt contiguous = fused B^T
    unsigned short* Wot = (unsigned short*)(ws + 4 * SLAB);
    unsigned short* QKV = (unsigned short*)(ws + 5 * SLAB);  // 96 MiB: [4096][12288]
    unsigned short* Vtb = Xb;   // alias: Xb dead after fused QKV GEMM
    unsigned short* Ob  = Wqt;  // alias: W*t dead after fused QKV GEMM

    // fused prep: 4 weight transposes + X convert in one launch
    k_prep<<<67584, 256, 0, stream>>>(X, Xb, Wq, Wk, Wv, Wo, Wqt);
    // fused QKV projection: C[4096][12288] = Xb * [Wqt|Wkt|Wvt]^T  (16x48=768 tiles)
    k_gemm256<unsigned short><<<768, 512, 0, stream>>>(Xb, Wqt, QKV, NTOK, 3 * HS, HS);
    // fused RoPE + V transpose (8192 + 16384 blocks)
    k_rope_tv<<<24576, 256, 0, stream>>>(QKV, Vtb);
    k_attn<<<dim3(SL / 128, BS * NH), 512, 0, stream>>>(QKV, Vtb, Ob);
    // output projection: out[4096][4096] = Ob * Wot^T  (16x16=256 tiles)
    k_gemm256<float><<<256, 512, 0, stream>>>(Ob, Wot, out, NTOK, HS, HS);
}